// Round 10
// baseline (657.709 us; speedup 1.0000x reference)
//
#include <hip/hip_runtime.h>
#include <hip/hip_bf16.h>

// GNN: 3x GCNConv (25->64->64->32) + global mean pool (256 graphs) + MLP head.
// Round 9: gathers are at the random-line-fetch roofline (3.78 TB/s constant
// across R6/R7/R9; ILP/ordering-insensitive). This round attacks the rest:
// (a) GEMM was LDS-issue-bound ~3:1 (b128+b32 per 4 FMAs); now 4x4 register
// tile with TRANSPOSED sIn[k][node] -> per 4-k: 2x ds_read_b128 for 16 FMAs
// = VALU-bound. (b) chunk-sorting proved worthless (R9 FETCH identical) ->
// bucket sort key back to 7 bits (NKEY 128), 3x less sort/scan work.
// Assumes N <= 131072 (17-bit src packing).

#define IN_DIM 25
#define HID 64
#define OUT3 32
#define BK_LOG 7
#define BK_NODES 128
#define MAXB 1024
#define EPB 16384
#define BCAP 8192

__device__ inline int ld_nt_i32(const int* p) {
    return __builtin_nontemporal_load(p);
}

// ---------------- stage 1: bucket histogram (LDS-privatized) ----------------
__global__ __launch_bounds__(256) void bucket_hist(const int* __restrict__ dst,
                                                   int* __restrict__ bhist, int nE) {
    __shared__ int h[MAXB];
    for (int i = threadIdx.x; i < MAXB; i += 256) h[i] = 0;
    __syncthreads();
    int e0 = blockIdx.x * 8192;
    int cnt = min(8192, nE - e0);
    for (int i = threadIdx.x; i < cnt; i += 256)
        atomicAdd(&h[(unsigned)dst[e0 + i] >> BK_LOG], 1);
    __syncthreads();
    for (int i = threadIdx.x; i < MAXB; i += 256)
        if (h[i]) atomicAdd(&bhist[i], h[i]);
}

// ---------------- stage 2: scan bucket counts (1 block) ----------------
__global__ __launch_bounds__(256) void bucket_scan(const int* __restrict__ bhist,
                                                   int* __restrict__ bbase,
                                                   int* __restrict__ cursor,
                                                   int* __restrict__ row_ptr,
                                                   int nb, int nE, int nN) {
    __shared__ int s4[256];
    int t = threadIdx.x;
    int v[4]; int sum = 0;
#pragma unroll
    for (int j = 0; j < 4; ++j) {
        int b = 4 * t + j;
        v[j] = (b < nb) ? bhist[b] : 0;
        sum += v[j];
    }
    s4[t] = sum;
    __syncthreads();
    for (int off = 1; off < 256; off <<= 1) {
        int mine = s4[t];
        int add = (t >= off) ? s4[t - off] : 0;
        __syncthreads();
        s4[t] = mine + add;
        __syncthreads();
    }
    int run = s4[t] - sum;
#pragma unroll
    for (int j = 0; j < 4; ++j) {
        int b = 4 * t + j;
        if (b < nb) { bbase[b] = run; cursor[b] = run; }
        run += v[j];
    }
    if (t == 0) { bbase[nb] = nE; row_ptr[nN] = nE; }
}

// ---------------- stage 3: partition into buckets (run writes) ----------
__global__ __launch_bounds__(256) void partition_kernel(
        const int* __restrict__ src, const int* __restrict__ dst,
        int* __restrict__ cursor, unsigned int* __restrict__ ebuf, int nE) {
    __shared__ int lh[MAXB];    // hist
    __shared__ int lrun[MAXB];  // global run base
    __shared__ int lcur[MAXB];  // local fill cursor
    int t = threadIdx.x;
    int e0 = blockIdx.x * EPB;
    int cnt = min(EPB, nE - e0);
    for (int i = t; i < MAXB; i += 256) lh[i] = 0;
    __syncthreads();
    for (int i = t; i < cnt; i += 256)
        atomicAdd(&lh[(unsigned)dst[e0 + i] >> BK_LOG], 1);
    __syncthreads();
#pragma unroll
    for (int j = 0; j < 4; ++j) {
        int b = 4 * t + j;
        int v = lh[b];
        lcur[b] = 0;
        if (v > 0) lrun[b] = atomicAdd(&cursor[b], v);
    }
    __syncthreads();
    for (int i = t; i < cnt; i += 256) {
        int d = dst[e0 + i];
        int s = src[e0 + i];
        int b = (unsigned)d >> BK_LOG;
        int lp = atomicAdd(&lcur[b], 1);
        ebuf[lrun[b] + lp] = ((unsigned)(d & (BK_NODES - 1)) << 17) | (unsigned)s;
    }
}

// ---------------- stage 4: per-bucket sort by dst_low (7-bit key) ----------
__global__ __launch_bounds__(256) void bucket_csr_kernel(
        unsigned int* __restrict__ ebuf, const int* __restrict__ bbase,
        float* __restrict__ dinv, int* __restrict__ row_ptr, int nN) {
    int b = blockIdx.x;
    int node_lo = b << BK_LOG;
    int nn = min(BK_NODES, nN - node_lo);
    int base = bbase[b];
    int cnt = bbase[b + 1] - base;
    if (cnt > BCAP) cnt = BCAP;
    __shared__ unsigned int in[BCAP];    // 32KB
    __shared__ unsigned int outb[BCAP];  // 32KB
    __shared__ int h2[BK_NODES], sc2[BK_NODES], lc2[BK_NODES];
    int t = threadIdx.x;
    for (int i = t; i < cnt; i += 256) in[i] = ebuf[base + i];
    if (t < BK_NODES) { h2[t] = 0; lc2[t] = 0; }
    __syncthreads();
    for (int i = t; i < cnt; i += 256) atomicAdd(&h2[in[i] >> 17], 1);
    __syncthreads();
    if (t < BK_NODES) sc2[t] = h2[t];
    __syncthreads();
    for (int off = 1; off < BK_NODES; off <<= 1) {
        int val = 0;
        if (t < BK_NODES) { val = sc2[t]; if (t >= off) val += sc2[t - off]; }
        __syncthreads();
        if (t < BK_NODES) sc2[t] = val;   // inclusive
        __syncthreads();
    }
    if (t < BK_NODES && t < nn) {
        int deg = h2[t];
        row_ptr[node_lo + t] = base + (sc2[t] - deg);
        dinv[node_lo + t] = rsqrtf((float)deg + 1.0f);   // + self loop
    }
    __syncthreads();
    for (int i = t; i < cnt; i += 256) {
        unsigned int w = in[i];
        int key = w >> 17;
        int lp = atomicAdd(&lc2[key], 1);
        outb[(sc2[key] - h2[key]) + lp] = w & 0x1FFFFu;
    }
    __syncthreads();
    for (int i = t; i < cnt; i += 256) ebuf[base + i] = outb[i];
}

// ---------------- pad + pre-scale helpers ----------------
__global__ void padx_kernel(const float* __restrict__ x, const float* __restrict__ dinv,
                            float* __restrict__ xp, int n) {
    int i = blockIdx.x * 256 + threadIdx.x;
    if (i < n * 32) {
        int node = i >> 5, c = i & 31;
        xp[i] = (c < IN_DIM) ? x[(size_t)node * IN_DIM + c] * dinv[node] : 0.f;
    }
}

__global__ void padw_kernel(const float* __restrict__ W1, float* __restrict__ W1p) {
    int i = blockIdx.x * 256 + threadIdx.x;
    if (i < 32 * HID) {
        int r = i >> 6, c = i & 63;
        W1p[i] = (r < IN_DIM) ? W1[r * HID + c] : 0.f;
    }
}

// ---------------- dense layer: out = in @ W [*dinv] [+bias,relu] -----------
// 4 nodes x 4 outs per thread; sIn transposed [k][node] so both LDS operands
// are ds_read_b128: per 4-k chunk 2x b128 per operand pair for 16 FMAs.
template<int INF, int OUTF, bool ACT, bool SCALE>
__global__ __launch_bounds__(256) void gemm_kernel(
        const float* __restrict__ in, const float* __restrict__ W,
        const float* __restrict__ bias, const float* __restrict__ dinv,
        float* __restrict__ out, int n) {
    constexpr int TPO = OUTF / 4;          // out-groups (16 or 8)
    constexpr int NG  = 256 / TPO;         // node-groups (16 or 32)
    constexpr int NPB = NG * 4;            // nodes per block (64 or 128)
    constexpr int LDN = NPB + 1;           // sIn row stride (odd -> bank-safe)
    __shared__ float sW[INF * OUTF];
    __shared__ float sIn[INF][LDN];
    int t = threadIdx.x;
    for (int i = t; i < INF * OUTF; i += 256) sW[i] = W[i];
    int node0 = blockIdx.x * NPB;
    // stage transposed: consecutive threads read consecutive float4 of a row
    for (int idx = t; idx < NPB * (INF / 4); idx += 256) {
        int ln = idx / (INF / 4);          // local node
        int k4 = idx % (INF / 4);
        int node = node0 + ln;
        float4 v = make_float4(0.f, 0.f, 0.f, 0.f);
        if (node < n) v = *(const float4*)&in[(size_t)node * INF + k4 * 4];
        sIn[k4 * 4 + 0][ln] = v.x;
        sIn[k4 * 4 + 1][ln] = v.y;
        sIn[k4 * 4 + 2][ln] = v.z;
        sIn[k4 * 4 + 3][ln] = v.w;
    }
    __syncthreads();
    int og = t % TPO;                      // out group
    int ng = t / TPO;                      // node group
    int of0 = og * 4;
    int ln0 = ng * 4;
    float acc[4][4];
#pragma unroll
    for (int i = 0; i < 4; ++i)
#pragma unroll
        for (int j = 0; j < 4; ++j) acc[i][j] = 0.f;
#pragma unroll
    for (int k = 0; k < INF; ++k) {
        const float4 av = *(const float4*)&sIn[k][ln0];
        const float4 wv = *(const float4*)&sW[k * OUTF + of0];
        const float* a = &av.x;
        const float* w = &wv.x;
#pragma unroll
        for (int i = 0; i < 4; ++i) {
            acc[i][0] += a[i] * w[0];
            acc[i][1] += a[i] * w[1];
            acc[i][2] += a[i] * w[2];
            acc[i][3] += a[i] * w[3];
        }
    }
    float4 bv = make_float4(0.f, 0.f, 0.f, 0.f);
    if (ACT) bv = *(const float4*)&bias[of0];
#pragma unroll
    for (int i = 0; i < 4; ++i) {
        int node = node0 + ln0 + i;
        if (node >= n) break;
        float4 r;
        r.x = acc[i][0]; r.y = acc[i][1]; r.z = acc[i][2]; r.w = acc[i][3];
        if (ACT) {
            r.x = fmaxf(r.x + bv.x, 0.f); r.y = fmaxf(r.y + bv.y, 0.f);
            r.z = fmaxf(r.z + bv.z, 0.f); r.w = fmaxf(r.w + bv.w, 0.f);
        }
        if (SCALE) {
            float s = dinv[node];
            r.x *= s; r.y *= s; r.z *= s; r.w *= s;
        }
        *(float4*)&out[(size_t)node * OUTF + of0] = r;
    }
}

// ---------------- flat CSR gather on PRE-SCALED rows ----------------
template<int F, bool ACT>
__global__ __launch_bounds__(256) void gather_kernel(
        const float* __restrict__ hp, const float* __restrict__ dinv,
        const int* __restrict__ row_ptr, const int* __restrict__ col,
        const float* __restrict__ bias, float* __restrict__ agg, int n) {
    constexpr int NPW = 64 / F;
    int wid  = (blockIdx.x * 256 + threadIdx.x) >> 6;
    int lane = threadIdx.x & 63;
    int sub  = lane / F;
    int f    = lane % F;
    int node = wid * NPW + sub;
    if (node >= n) return;
    float a0 = hp[(size_t)node * F + f];   // self loop (pre-scaled)
    float a1 = 0.f, a2 = 0.f, a3 = 0.f;
    int e = row_ptr[node], end = row_ptr[node + 1];
    for (; e + 16 <= end; e += 16) {
        int c[16];
#pragma unroll
        for (int j = 0; j < 16; ++j) c[j] = ld_nt_i32(&col[e + j]);
        float v[16];
#pragma unroll
        for (int j = 0; j < 16; ++j) v[j] = hp[(size_t)c[j] * F + f];
#pragma unroll
        for (int j = 0; j < 4; ++j) {
            a0 += v[4 * j];     a1 += v[4 * j + 1];
            a2 += v[4 * j + 2]; a3 += v[4 * j + 3];
        }
    }
    for (; e + 4 <= end; e += 4) {
        int c0 = ld_nt_i32(&col[e]),     c1 = ld_nt_i32(&col[e + 1]);
        int c2 = ld_nt_i32(&col[e + 2]), c3 = ld_nt_i32(&col[e + 3]);
        a0 += hp[(size_t)c0 * F + f]; a1 += hp[(size_t)c1 * F + f];
        a2 += hp[(size_t)c2 * F + f]; a3 += hp[(size_t)c3 * F + f];
    }
    for (; e < end; ++e) a0 += hp[(size_t)ld_nt_i32(&col[e]) * F + f];
    float acc = ((a0 + a1) + (a2 + a3)) * dinv[node];
    float r = ACT ? fmaxf(acc + bias[f], 0.f) : acc;
    agg[(size_t)node * F + f] = r;
}

// ---------------- mean pool ----------------
__global__ __launch_bounds__(256) void pool_kernel(
        const float* __restrict__ h3, const int* __restrict__ batch,
        int n, float* __restrict__ pool) {
    int g = blockIdx.x;
    int lo = 0, hi = n;
    while (lo < hi) { int m = (lo + hi) >> 1; if (batch[m] < g) lo = m + 1; else hi = m; }
    int s = lo;
    hi = n;
    while (lo < hi) { int m = (lo + hi) >> 1; if (batch[m] < g + 1) lo = m + 1; else hi = m; }
    int e = lo;
    constexpr int F = OUT3;
    int ln = threadIdx.x / F;
    int f  = threadIdx.x % F;
    float acc = 0.f;
    for (int i = s + ln; i < e; i += 8)
        acc += h3[(size_t)i * F + f];
    __shared__ float red[8][F];
    red[ln][f] = acc;
    __syncthreads();
    if (ln == 0) {
        float t = 0.f;
#pragma unroll
        for (int j = 0; j < 8; ++j) t += red[j][f];
        float cnt = (float)((e - s) > 0 ? (e - s) : 1);
        pool[g * F + f] = t / cnt;
    }
}

// ---------------- head ----------------
__global__ __launch_bounds__(256) void head_kernel(
        const float* __restrict__ pool, const float* __restrict__ Wh1,
        const float* __restrict__ bh1, const float* __restrict__ Wh2,
        const float* __restrict__ bh2, float* __restrict__ out) {
    __shared__ float sW1[32 * 32];
    __shared__ float sb1[32];
    __shared__ float sW2[32];
    int t = threadIdx.x;
    for (int i = t; i < 1024; i += 256) sW1[i] = Wh1[i];
    if (t < 32) { sb1[t] = bh1[t]; sW2[t] = Wh2[t]; }
    __syncthreads();
    int g = t;
    float y = bh2[0];
    const float* p = &pool[g * 32];
#pragma unroll 4
    for (int j = 0; j < 32; ++j) {
        float a = sb1[j];
#pragma unroll
        for (int k = 0; k < 32; ++k) a += p[k] * sW1[k * 32 + j];
        y += fmaxf(a, 0.f) * sW2[j];
    }
    out[g] = y;
}

extern "C" void kernel_launch(void* const* d_in, const int* in_sizes, int n_in,
                              void* d_out, int out_size, void* d_ws, size_t ws_size,
                              hipStream_t stream) {
    const float* x    = (const float*)d_in[0];
    const int*   ei   = (const int*)  d_in[1];
    const int*   batch= (const int*)  d_in[2];
    const float* W1   = (const float*)d_in[3];
    const float* b1   = (const float*)d_in[4];
    const float* W2   = (const float*)d_in[5];
    const float* b2   = (const float*)d_in[6];
    const float* W3   = (const float*)d_in[7];
    const float* b3   = (const float*)d_in[8];
    const float* Wh1  = (const float*)d_in[9];
    const float* bh1  = (const float*)d_in[10];
    const float* Wh2  = (const float*)d_in[11];
    const float* bh2  = (const float*)d_in[12];
    float* out = (float*)d_out;

    const int N = in_sizes[0] / IN_DIM;
    const int E = in_sizes[1] / 2;
    const int* src = ei;
    const int* dst = ei + E;
    const int NB = (N + BK_NODES - 1) >> BK_LOG;

    // workspace layout (all 4B elements)
    char* base = (char*)d_ws;
    unsigned int* ebuf = (unsigned int*)base;       base += (size_t)E * 4;
    int*   bhist   = (int*)base;                    base += (size_t)MAXB * 4;
    int*   bbase   = (int*)base;                    base += (size_t)(MAXB + 1) * 4;
    int*   cursor  = (int*)base;                    base += (size_t)MAXB * 4;
    int*   row_ptr = (int*)base;                    base += (size_t)(N + 1) * 4;
    float* dinv    = (float*)base;                  base += (size_t)N * 4;
    float* W1p     = (float*)base;                  base += (size_t)32 * HID * 4;
    float* bufA    = (float*)base;                  base += (size_t)N * HID * 4;
    float* bufB    = (float*)base;                  base += (size_t)N * HID * 4;
    float* pool    = (float*)base;

    // ---- CSR build ----
    hipMemsetAsync(bhist, 0, (size_t)MAXB * sizeof(int), stream);
    bucket_hist<<<(E + 8191) / 8192, 256, 0, stream>>>(dst, bhist, E);
    bucket_scan<<<1, 256, 0, stream>>>(bhist, bbase, cursor, row_ptr, NB, E, N);
    partition_kernel<<<(E + EPB - 1) / EPB, 256, 0, stream>>>(src, dst, cursor, ebuf, E);
    bucket_csr_kernel<<<NB, 256, 0, stream>>>(ebuf, bbase, dinv, row_ptr, N);
    const int* col = (const int*)ebuf;

    // ---- layer 1 (reordered): aggX = A_hat Xp' ; h1 = relu(aggX @ W1p + b1)
    padx_kernel<<<((size_t)N * 32 + 255) / 256, 256, 0, stream>>>(x, dinv, bufB, N);
    padw_kernel<<<(32 * HID + 255) / 256, 256, 0, stream>>>(W1, W1p);
    gather_kernel<32, false><<<(N + 7) / 8, 256, 0, stream>>>(bufB, dinv, row_ptr, col, nullptr, bufA, N);
    gemm_kernel<32, HID, true, false><<<(N + 63) / 64, 256, 0, stream>>>(bufA, W1p, b1, nullptr, bufB, N);

    // ---- layer 2: t2' = (h1 @ W2)*dinv ; h2 = relu(dinv*(sum t2') + b2) ----
    gemm_kernel<HID, HID, false, true><<<(N + 63) / 64, 256, 0, stream>>>(bufB, W2, nullptr, dinv, bufA, N);
    gather_kernel<HID, true><<<(N + 3) / 4, 256, 0, stream>>>(bufA, dinv, row_ptr, col, b2, bufB, N);

    // ---- layer 3: t3' = (h2 @ W3)*dinv ; h3 = relu(dinv*(sum t3') + b3) ----
    gemm_kernel<HID, OUT3, false, true><<<(N + 127) / 128, 256, 0, stream>>>(bufB, W3, nullptr, dinv, bufA, N);
    gather_kernel<OUT3, true><<<(N + 7) / 8, 256, 0, stream>>>(bufA, dinv, row_ptr, col, b3, bufB, N);

    // ---- pool + head ----
    pool_kernel<<<256, 256, 0, stream>>>(bufB, batch, N, pool);
    head_kernel<<<1, 256, 0, stream>>>(pool, Wh1, bh1, Wh2, bh2, out);
}

// Round 11
// 616.281 us; speedup vs baseline: 1.0672x; 1.0672x over previous
//
#include <hip/hip_runtime.h>
#include <hip/hip_bf16.h>

// GNN: 3x GCNConv (25->64->64->32) + global mean pool (256 graphs) + MLP head.
// Round 10: best-known-component assembly. Measured component A/Bs:
//  - gemm: simple TPN-per-node version (R7) beats 4x4 transposed tile (R10,
//    +28us) at these tiny K.
//  - partition: 96KB LDS staged sweep (R7) beats direct-run writes (R9,
//    +16-25us) -- fully coalesced ebuf writes win despite 1 block/CU.
//  - bucket sort key: 7-bit dst_low (R9) -- chunk-sorting proved worthless.
//  - gathers: flat, unroll 16, 4 accs -- at 5.7 TB/s logical (~91% of
//    achievable BW); structural roofline for this algorithm.
//  - padw folded into padx (one fewer dispatch).
// Assumes N <= 131072 (17-bit src packing).

#define IN_DIM 25
#define HID 64
#define OUT3 32
#define BK_LOG 7
#define BK_NODES 128
#define MAXB 1024
#define EPB 16384
#define BCAP 8192

__device__ inline int ld_nt_i32(const int* p) {
    return __builtin_nontemporal_load(p);
}

// ---------------- stage 1: bucket histogram (LDS-privatized) ----------------
__global__ __launch_bounds__(256) void bucket_hist(const int* __restrict__ dst,
                                                   int* __restrict__ bhist, int nE) {
    __shared__ int h[MAXB];
    for (int i = threadIdx.x; i < MAXB; i += 256) h[i] = 0;
    __syncthreads();
    int e0 = blockIdx.x * 8192;
    int cnt = min(8192, nE - e0);
    for (int i = threadIdx.x; i < cnt; i += 256)
        atomicAdd(&h[(unsigned)dst[e0 + i] >> BK_LOG], 1);
    __syncthreads();
    for (int i = threadIdx.x; i < MAXB; i += 256)
        if (h[i]) atomicAdd(&bhist[i], h[i]);
}

// ---------------- stage 2: scan bucket counts (1 block) ----------------
__global__ __launch_bounds__(256) void bucket_scan(const int* __restrict__ bhist,
                                                   int* __restrict__ bbase,
                                                   int* __restrict__ cursor,
                                                   int* __restrict__ row_ptr,
                                                   int nb, int nE, int nN) {
    __shared__ int s4[256];
    int t = threadIdx.x;
    int v[4]; int sum = 0;
#pragma unroll
    for (int j = 0; j < 4; ++j) {
        int b = 4 * t + j;
        v[j] = (b < nb) ? bhist[b] : 0;
        sum += v[j];
    }
    s4[t] = sum;
    __syncthreads();
    for (int off = 1; off < 256; off <<= 1) {
        int mine = s4[t];
        int add = (t >= off) ? s4[t - off] : 0;
        __syncthreads();
        s4[t] = mine + add;
        __syncthreads();
    }
    int run = s4[t] - sum;
#pragma unroll
    for (int j = 0; j < 4; ++j) {
        int b = 4 * t + j;
        if (b < nb) { bbase[b] = run; cursor[b] = run; }
        run += v[j];
    }
    if (t == 0) { bbase[nb] = nE; row_ptr[nN] = nE; }
}

// ---------------- stage 3: partition into buckets (staged, coalesced) ------
__global__ __launch_bounds__(256) void partition_kernel(
        const int* __restrict__ src, const int* __restrict__ dst,
        int* __restrict__ cursor, unsigned int* __restrict__ ebuf, int nE) {
    __shared__ int lh[MAXB];              // hist -> local excl scan
    __shared__ int lrun[MAXB];            // global run base
    __shared__ int lcur[MAXB];            // local fill cursor
    __shared__ int swp[256];
    __shared__ unsigned int stg[EPB];     // bucket-sorted packed words (64KB)
    __shared__ unsigned short sbk[EPB];   // bucket id per sorted slot (32KB)
    int t = threadIdx.x;
    int e0 = blockIdx.x * EPB;
    int cnt = min(EPB, nE - e0);
    for (int i = t; i < MAXB; i += 256) lh[i] = 0;
    __syncthreads();
    for (int i = t; i < cnt; i += 256)
        atomicAdd(&lh[(unsigned)dst[e0 + i] >> BK_LOG], 1);
    __syncthreads();
    int v[4]; int sum = 0;
#pragma unroll
    for (int j = 0; j < 4; ++j) { v[j] = lh[4 * t + j]; sum += v[j]; }
    swp[t] = sum;
    __syncthreads();
    for (int off = 1; off < 256; off <<= 1) {
        int mine = swp[t];
        int add = (t >= off) ? swp[t - off] : 0;
        __syncthreads();
        swp[t] = mine + add;
        __syncthreads();
    }
    int run = swp[t] - sum;
#pragma unroll
    for (int j = 0; j < 4; ++j) {
        int b = 4 * t + j;
        lh[b] = run;
        lcur[b] = 0;
        if (v[j] > 0) lrun[b] = atomicAdd(&cursor[b], v[j]);
        run += v[j];
    }
    __syncthreads();
    for (int i = t; i < cnt; i += 256) {
        int d = dst[e0 + i];
        int s = src[e0 + i];
        int b = (unsigned)d >> BK_LOG;
        int lp = atomicAdd(&lcur[b], 1);
        int slot = lh[b] + lp;
        stg[slot] = ((unsigned)(d & (BK_NODES - 1)) << 17) | (unsigned)s;
        sbk[slot] = (unsigned short)b;
    }
    __syncthreads();
    for (int i = t; i < cnt; i += 256) {
        int b = sbk[i];
        int g = lrun[b] + (i - lh[b]);
        ebuf[g] = stg[i];
    }
}

// ---------------- stage 4: per-bucket sort by dst_low (7-bit key) ----------
__global__ __launch_bounds__(256) void bucket_csr_kernel(
        unsigned int* __restrict__ ebuf, const int* __restrict__ bbase,
        float* __restrict__ dinv, int* __restrict__ row_ptr, int nN) {
    int b = blockIdx.x;
    int node_lo = b << BK_LOG;
    int nn = min(BK_NODES, nN - node_lo);
    int base = bbase[b];
    int cnt = bbase[b + 1] - base;
    if (cnt > BCAP) cnt = BCAP;
    __shared__ unsigned int in[BCAP];    // 32KB
    __shared__ unsigned int outb[BCAP];  // 32KB
    __shared__ int h2[BK_NODES], sc2[BK_NODES], lc2[BK_NODES];
    int t = threadIdx.x;
    for (int i = t; i < cnt; i += 256) in[i] = ebuf[base + i];
    if (t < BK_NODES) { h2[t] = 0; lc2[t] = 0; }
    __syncthreads();
    for (int i = t; i < cnt; i += 256) atomicAdd(&h2[in[i] >> 17], 1);
    __syncthreads();
    if (t < BK_NODES) sc2[t] = h2[t];
    __syncthreads();
    for (int off = 1; off < BK_NODES; off <<= 1) {
        int val = 0;
        if (t < BK_NODES) { val = sc2[t]; if (t >= off) val += sc2[t - off]; }
        __syncthreads();
        if (t < BK_NODES) sc2[t] = val;   // inclusive
        __syncthreads();
    }
    if (t < BK_NODES && t < nn) {
        int deg = h2[t];
        row_ptr[node_lo + t] = base + (sc2[t] - deg);
        dinv[node_lo + t] = rsqrtf((float)deg + 1.0f);   // + self loop
    }
    __syncthreads();
    for (int i = t; i < cnt; i += 256) {
        unsigned int w = in[i];
        int key = w >> 17;
        int lp = atomicAdd(&lc2[key], 1);
        outb[(sc2[key] - h2[key]) + lp] = w & 0x1FFFFu;
    }
    __syncthreads();
    for (int i = t; i < cnt; i += 256) ebuf[base + i] = outb[i];
}

// ---------------- pad X (pre-scaled) + pad W1 in one dispatch ----------------
__global__ void padx_kernel(const float* __restrict__ x, const float* __restrict__ dinv,
                            float* __restrict__ xp, const float* __restrict__ W1,
                            float* __restrict__ W1p, int n, int nbx) {
    if ((int)blockIdx.x >= nbx) {   // tail blocks: pad W1 (32x64)
        int i = (blockIdx.x - nbx) * 256 + threadIdx.x;
        if (i < 32 * HID) {
            int r = i >> 6, c = i & 63;
            W1p[i] = (r < IN_DIM) ? W1[r * HID + c] : 0.f;
        }
        return;
    }
    int i = blockIdx.x * 256 + threadIdx.x;
    if (i < n * 32) {
        int node = i >> 5, c = i & 31;
        xp[i] = (c < IN_DIM) ? x[(size_t)node * IN_DIM + c] * dinv[node] : 0.f;
    }
}

// ---------------- dense layer: out = in @ W [*dinv] [+bias,relu] -----------
// Simple TPN-threads-per-node version (fastest measured).
template<int INF, int OUTF, bool ACT, bool SCALE>
__global__ __launch_bounds__(256) void gemm_kernel(
        const float* __restrict__ in, const float* __restrict__ W,
        const float* __restrict__ bias, const float* __restrict__ dinv,
        float* __restrict__ out, int n) {
    constexpr int TPN = OUTF / 4;
    constexpr int NPB = 256 / TPN;
    constexpr int LDK = INF + 4;
    __shared__ float sW[INF * OUTF];
    __shared__ float sIn[NPB][LDK];
    for (int i = threadIdx.x; i < INF * OUTF; i += 256) sW[i] = W[i];
    int node0 = blockIdx.x * NPB;
    for (int i = threadIdx.x; i < NPB * INF; i += 256) {
        int ln = i / INF, k = i % INF;
        int node = node0 + ln;
        sIn[ln][k] = (node < n) ? in[(size_t)node * INF + k] : 0.f;
    }
    __syncthreads();
    int g   = threadIdx.x / TPN;
    int of0 = (threadIdx.x % TPN) * 4;
    int node = node0 + g;
    float4 acc = make_float4(0.f, 0.f, 0.f, 0.f);
#pragma unroll
    for (int k = 0; k < INF; ++k) {
        float aj = sIn[g][k];
        const float4 wv = *(const float4*)&sW[k * OUTF + of0];
        acc.x += aj * wv.x; acc.y += aj * wv.y;
        acc.z += aj * wv.z; acc.w += aj * wv.w;
    }
    if (ACT) {
        const float4 bv = *(const float4*)&bias[of0];
        acc.x = fmaxf(acc.x + bv.x, 0.f);
        acc.y = fmaxf(acc.y + bv.y, 0.f);
        acc.z = fmaxf(acc.z + bv.z, 0.f);
        acc.w = fmaxf(acc.w + bv.w, 0.f);
    }
    if (node < n) {
        if (SCALE) {
            float s = dinv[node];
            acc.x *= s; acc.y *= s; acc.z *= s; acc.w *= s;
        }
        *(float4*)&out[(size_t)node * OUTF + of0] = acc;
    }
}

// ---------------- flat CSR gather on PRE-SCALED rows ----------------
template<int F, bool ACT>
__global__ __launch_bounds__(256) void gather_kernel(
        const float* __restrict__ hp, const float* __restrict__ dinv,
        const int* __restrict__ row_ptr, const int* __restrict__ col,
        const float* __restrict__ bias, float* __restrict__ agg, int n) {
    constexpr int NPW = 64 / F;
    int wid  = (blockIdx.x * 256 + threadIdx.x) >> 6;
    int lane = threadIdx.x & 63;
    int sub  = lane / F;
    int f    = lane % F;
    int node = wid * NPW + sub;
    if (node >= n) return;
    float a0 = hp[(size_t)node * F + f];   // self loop (pre-scaled)
    float a1 = 0.f, a2 = 0.f, a3 = 0.f;
    int e = row_ptr[node], end = row_ptr[node + 1];
    for (; e + 16 <= end; e += 16) {
        int c[16];
#pragma unroll
        for (int j = 0; j < 16; ++j) c[j] = ld_nt_i32(&col[e + j]);
        float v[16];
#pragma unroll
        for (int j = 0; j < 16; ++j) v[j] = hp[(size_t)c[j] * F + f];
#pragma unroll
        for (int j = 0; j < 4; ++j) {
            a0 += v[4 * j];     a1 += v[4 * j + 1];
            a2 += v[4 * j + 2]; a3 += v[4 * j + 3];
        }
    }
    for (; e + 4 <= end; e += 4) {
        int c0 = ld_nt_i32(&col[e]),     c1 = ld_nt_i32(&col[e + 1]);
        int c2 = ld_nt_i32(&col[e + 2]), c3 = ld_nt_i32(&col[e + 3]);
        a0 += hp[(size_t)c0 * F + f]; a1 += hp[(size_t)c1 * F + f];
        a2 += hp[(size_t)c2 * F + f]; a3 += hp[(size_t)c3 * F + f];
    }
    for (; e < end; ++e) a0 += hp[(size_t)ld_nt_i32(&col[e]) * F + f];
    float acc = ((a0 + a1) + (a2 + a3)) * dinv[node];
    float r = ACT ? fmaxf(acc + bias[f], 0.f) : acc;
    agg[(size_t)node * F + f] = r;
}

// ---------------- mean pool ----------------
__global__ __launch_bounds__(256) void pool_kernel(
        const float* __restrict__ h3, const int* __restrict__ batch,
        int n, float* __restrict__ pool) {
    int g = blockIdx.x;
    int lo = 0, hi = n;
    while (lo < hi) { int m = (lo + hi) >> 1; if (batch[m] < g) lo = m + 1; else hi = m; }
    int s = lo;
    hi = n;
    while (lo < hi) { int m = (lo + hi) >> 1; if (batch[m] < g + 1) lo = m + 1; else hi = m; }
    int e = lo;
    constexpr int F = OUT3;
    int ln = threadIdx.x / F;
    int f  = threadIdx.x % F;
    float acc = 0.f;
    for (int i = s + ln; i < e; i += 8)
        acc += h3[(size_t)i * F + f];
    __shared__ float red[8][F];
    red[ln][f] = acc;
    __syncthreads();
    if (ln == 0) {
        float t = 0.f;
#pragma unroll
        for (int j = 0; j < 8; ++j) t += red[j][f];
        float cnt = (float)((e - s) > 0 ? (e - s) : 1);
        pool[g * F + f] = t / cnt;
    }
}

// ---------------- head ----------------
__global__ __launch_bounds__(256) void head_kernel(
        const float* __restrict__ pool, const float* __restrict__ Wh1,
        const float* __restrict__ bh1, const float* __restrict__ Wh2,
        const float* __restrict__ bh2, float* __restrict__ out) {
    __shared__ float sW1[32 * 32];
    __shared__ float sb1[32];
    __shared__ float sW2[32];
    int t = threadIdx.x;
    for (int i = t; i < 1024; i += 256) sW1[i] = Wh1[i];
    if (t < 32) { sb1[t] = bh1[t]; sW2[t] = Wh2[t]; }
    __syncthreads();
    int g = t;
    float y = bh2[0];
    const float* p = &pool[g * 32];
#pragma unroll 4
    for (int j = 0; j < 32; ++j) {
        float a = sb1[j];
#pragma unroll
        for (int k = 0; k < 32; ++k) a += p[k] * sW1[k * 32 + j];
        y += fmaxf(a, 0.f) * sW2[j];
    }
    out[g] = y;
}

extern "C" void kernel_launch(void* const* d_in, const int* in_sizes, int n_in,
                              void* d_out, int out_size, void* d_ws, size_t ws_size,
                              hipStream_t stream) {
    const float* x    = (const float*)d_in[0];
    const int*   ei   = (const int*)  d_in[1];
    const int*   batch= (const int*)  d_in[2];
    const float* W1   = (const float*)d_in[3];
    const float* b1   = (const float*)d_in[4];
    const float* W2   = (const float*)d_in[5];
    const float* b2   = (const float*)d_in[6];
    const float* W3   = (const float*)d_in[7];
    const float* b3   = (const float*)d_in[8];
    const float* Wh1  = (const float*)d_in[9];
    const float* bh1  = (const float*)d_in[10];
    const float* Wh2  = (const float*)d_in[11];
    const float* bh2  = (const float*)d_in[12];
    float* out = (float*)d_out;

    const int N = in_sizes[0] / IN_DIM;
    const int E = in_sizes[1] / 2;
    const int* src = ei;
    const int* dst = ei + E;
    const int NB = (N + BK_NODES - 1) >> BK_LOG;

    // workspace layout (all 4B elements)
    char* base = (char*)d_ws;
    unsigned int* ebuf = (unsigned int*)base;       base += (size_t)E * 4;
    int*   bhist   = (int*)base;                    base += (size_t)MAXB * 4;
    int*   bbase   = (int*)base;                    base += (size_t)(MAXB + 1) * 4;
    int*   cursor  = (int*)base;                    base += (size_t)MAXB * 4;
    int*   row_ptr = (int*)base;                    base += (size_t)(N + 1) * 4;
    float* dinv    = (float*)base;                  base += (size_t)N * 4;
    float* W1p     = (float*)base;                  base += (size_t)32 * HID * 4;
    float* bufA    = (float*)base;                  base += (size_t)N * HID * 4;
    float* bufB    = (float*)base;                  base += (size_t)N * HID * 4;
    float* pool    = (float*)base;

    // ---- CSR build ----
    hipMemsetAsync(bhist, 0, (size_t)MAXB * sizeof(int), stream);
    bucket_hist<<<(E + 8191) / 8192, 256, 0, stream>>>(dst, bhist, E);
    bucket_scan<<<1, 256, 0, stream>>>(bhist, bbase, cursor, row_ptr, NB, E, N);
    partition_kernel<<<(E + EPB - 1) / EPB, 256, 0, stream>>>(src, dst, cursor, ebuf, E);
    bucket_csr_kernel<<<NB, 256, 0, stream>>>(ebuf, bbase, dinv, row_ptr, N);
    const int* col = (const int*)ebuf;

    // ---- layer 1 (reordered): aggX = A_hat Xp' ; h1 = relu(aggX @ W1p + b1)
    {
        int nbx = ((int)((size_t)N * 32) + 255) / 256;
        padx_kernel<<<nbx + 8, 256, 0, stream>>>(x, dinv, bufB, W1, W1p, N, nbx);
    }
    gather_kernel<32, false><<<(N + 7) / 8, 256, 0, stream>>>(bufB, dinv, row_ptr, col, nullptr, bufA, N);
    gemm_kernel<32, HID, true, false><<<(N + 15) / 16, 256, 0, stream>>>(bufA, W1p, b1, nullptr, bufB, N);

    // ---- layer 2: t2' = (h1 @ W2)*dinv ; h2 = relu(dinv*(sum t2') + b2) ----
    gemm_kernel<HID, HID, false, true><<<(N + 15) / 16, 256, 0, stream>>>(bufB, W2, nullptr, dinv, bufA, N);
    gather_kernel<HID, true><<<(N + 3) / 4, 256, 0, stream>>>(bufA, dinv, row_ptr, col, b2, bufB, N);

    // ---- layer 3: t3' = (h2 @ W3)*dinv ; h3 = relu(dinv*(sum t3') + b3) ----
    gemm_kernel<HID, OUT3, false, true><<<(N + 31) / 32, 256, 0, stream>>>(bufB, W3, nullptr, dinv, bufA, N);
    gather_kernel<OUT3, true><<<(N + 7) / 8, 256, 0, stream>>>(bufA, dinv, row_ptr, col, b3, bufB, N);

    // ---- pool + head ----
    pool_kernel<<<256, 256, 0, stream>>>(bufB, batch, N, pool);
    head_kernel<<<1, 256, 0, stream>>>(pool, Wh1, bh1, Wh2, bh2, out);
}